// Round 4
// baseline (876.242 us; speedup 1.0000x reference)
//
#include <hip/hip_runtime.h>
#include <hip/hip_bf16.h>
#include <math.h>

#define SEQ    2048
#define BATCH  2
#define DM     1024
#define NH     16
#define DH     64
#define BS_ROWS 4096
#define KDIM   1024

typedef __attribute__((ext_vector_type(8))) short short8v;
typedef __attribute__((ext_vector_type(4))) float f32x4;
typedef unsigned short ushort_t;

__device__ __forceinline__ unsigned short f2bf(float f) {
  union { float f; unsigned u; } v; v.f = f;
  unsigned r = (v.u + 0x7FFF + ((v.u >> 16) & 1)) >> 16;
  return (unsigned short)r;
}
__device__ __forceinline__ float bf2f(unsigned short h) {
  union { unsigned u; float f; } v; v.u = ((unsigned)h) << 16;
  return v.f;
}

// async global->LDS, 16B per lane; lds ptr must be wave-uniform base (+lane*16 implied)
__device__ __forceinline__ void gl16(const void* g, void* l) {
  __builtin_amdgcn_global_load_lds(
      (const __attribute__((address_space(1))) unsigned int*)g,
      (__attribute__((address_space(3))) unsigned int*)l,
      16, 0, 0);
}

// ---------------------------------------------------------------------------
// fp32 -> hi/lo bf16 split (8 elems/thread)
// ---------------------------------------------------------------------------
__global__ __launch_bounds__(256)
void split_f32(const float* __restrict__ src, ushort_t* __restrict__ h,
               ushort_t* __restrict__ l, int n8)
{
  const int i = blockIdx.x * 256 + threadIdx.x;
  if (i >= n8) return;
  const float4 v0 = ((const float4*)src)[2 * i];
  const float4 v1 = ((const float4*)src)[2 * i + 1];
  const float vals[8] = {v0.x, v0.y, v0.z, v0.w, v1.x, v1.y, v1.z, v1.w};
  short8v hv, lv;
  #pragma unroll
  for (int e = 0; e < 8; e++) {
    const unsigned short hb = f2bf(vals[e]);
    hv[e] = (short)hb;
    lv[e] = (short)f2bf(vals[e] - bf2f(hb));
  }
  ((short8v*)h)[i] = hv;
  ((short8v*)l)[i] = lv;
}

// ---------------------------------------------------------------------------
// weight transpose + split: Wt[z][hi][n][k] = hi(W[k][n]), Wt[z][lo][n][k] = lo
// WT packed: base + z*2M + sel*1M  (u16 elems)
// ---------------------------------------------------------------------------
__global__ __launch_bounds__(256)
void wtrans(const float* __restrict__ w0, const float* __restrict__ w1,
            const float* __restrict__ w2, const float* __restrict__ w3,
            ushort_t* __restrict__ WT)
{
  __shared__ float tile[64][65];
  const int z = blockIdx.z;
  const float* __restrict__ W = (z == 0) ? w0 : (z == 1) ? w1 : (z == 2) ? w2 : w3;
  ushort_t* __restrict__ Oh = WT + (size_t)z * 2097152;
  ushort_t* __restrict__ Ol = Oh + 1048576;

  const int n0 = blockIdx.x * 64, k0 = blockIdx.y * 64;
  const int r  = threadIdx.x >> 2;
  const int c0 = (threadIdx.x & 3) * 16;

  #pragma unroll
  for (int i = 0; i < 4; i++) {
    const float4 v = *(const float4*)&W[(size_t)(k0 + r) * KDIM + n0 + c0 + 4 * i];
    tile[r][c0 + 4 * i + 0] = v.x; tile[r][c0 + 4 * i + 1] = v.y;
    tile[r][c0 + 4 * i + 2] = v.z; tile[r][c0 + 4 * i + 3] = v.w;
  }
  __syncthreads();

  #pragma unroll
  for (int c = 0; c < 2; c++) {
    short8v hv, lv;
    #pragma unroll
    for (int e = 0; e < 8; e++) {
      const float x = tile[c0 + c * 8 + e][r];
      const unsigned short hb = f2bf(x);
      hv[e] = (short)hb;
      lv[e] = (short)f2bf(x - bf2f(hb));
    }
    const size_t off = (size_t)(n0 + r) * KDIM + k0 + c0 + c * 8;
    *(short8v*)&Oh[off] = hv;
    *(short8v*)&Ol[off] = lv;
  }
}

// ---------------------------------------------------------------------------
// Split-bf16 MFMA GEMM: C[M=4096,N=1024] = (Ah+Al) @ (Bh+Bl)^T
// A row-major [M][K]; B = pre-transposed weight Wt[n][k].
// 128x128 tile, BK=32, 4 waves, 4x4 16x16x32 frags/wave, 3 MFMAs per frag pair.
// mode 0: RoPE+split -> Qh/Ql (scale 1/32); 1: RoPE+split -> Kh/Kl;
// mode 2: Vt bf16 transposed; 3: fp32 C.
// ---------------------------------------------------------------------------
__global__ __launch_bounds__(256)
void mfma_gemm(const ushort_t* __restrict__ Ah, const ushort_t* __restrict__ Al,
               const ushort_t* __restrict__ WT, int zbase,
               ushort_t* __restrict__ Qh, ushort_t* __restrict__ Ql,
               ushort_t* __restrict__ Kh, ushort_t* __restrict__ Kl,
               ushort_t* __restrict__ Vt, float* __restrict__ Cf)
{
  const int mode = zbase + blockIdx.z;
  const ushort_t* __restrict__ Bh = WT + (size_t)mode * 2097152;
  const ushort_t* __restrict__ Bl = Bh + 1048576;

  __shared__ ushort_t Ash[128][32];
  __shared__ ushort_t Asl[128][32];
  __shared__ ushort_t Bsh[128][32];
  __shared__ ushort_t Bsl[128][32];

  const int t = threadIdx.x;
  const int lane = t & 63, w = t >> 6;
  const int l4 = lane & 15, lh = lane >> 4;
  const int wm = w >> 1, wn = w & 1;
  const int row0 = blockIdx.y * 128, col0 = blockIdx.x * 128;

  const int srow = t >> 2;           // 0..63
  const int scol = (t & 3) * 8;      // 0,8,16,24

  f32x4 acc[4][4];
  #pragma unroll
  for (int i = 0; i < 4; i++)
    #pragma unroll
    for (int j = 0; j < 4; j++) acc[i][j] = (f32x4){0.f, 0.f, 0.f, 0.f};

  for (int k0 = 0; k0 < KDIM; k0 += 32) {
    #pragma unroll
    for (int r = 0; r < 2; r++) {
      const int row = srow + r * 64;
      const size_t gA = (size_t)(row0 + row) * KDIM + k0 + scol;
      const size_t gB = (size_t)(col0 + row) * KDIM + k0 + scol;
      const int lo = w * 1024 + r * 4096;     // byte offset (wave-uniform)
      gl16(Ah + gA, (char*)Ash + lo);
      gl16(Al + gA, (char*)Asl + lo);
      gl16(Bh + gB, (char*)Bsh + lo);
      gl16(Bl + gB, (char*)Bsl + lo);
    }
    __syncthreads();

    short8v fah[4], fal[4], fbh[4], fbl[4];
    #pragma unroll
    for (int mf = 0; mf < 4; mf++) {
      const int rr = wm * 64 + mf * 16 + l4;
      fah[mf] = *(const short8v*)&Ash[rr][lh * 8];
      fal[mf] = *(const short8v*)&Asl[rr][lh * 8];
    }
    #pragma unroll
    for (int nf = 0; nf < 4; nf++) {
      const int rr = wn * 64 + nf * 16 + l4;
      fbh[nf] = *(const short8v*)&Bsh[rr][lh * 8];
      fbl[nf] = *(const short8v*)&Bsl[rr][lh * 8];
    }
    #pragma unroll
    for (int mf = 0; mf < 4; mf++)
      #pragma unroll
      for (int nf = 0; nf < 4; nf++) {
        acc[mf][nf] = __builtin_amdgcn_mfma_f32_16x16x32_bf16(fah[mf], fbh[nf], acc[mf][nf], 0, 0, 0);
        acc[mf][nf] = __builtin_amdgcn_mfma_f32_16x16x32_bf16(fah[mf], fbl[nf], acc[mf][nf], 0, 0, 0);
        acc[mf][nf] = __builtin_amdgcn_mfma_f32_16x16x32_bf16(fal[mf], fbh[nf], acc[mf][nf], 0, 0, 0);
      }
    __syncthreads();
  }

  // ---- epilogues (C-layout: col = ..+l4, row = ..+lh*4+j) ----
  if (mode <= 1) {
    const float scale = (mode == 0) ? 0.03125f : 1.0f;
    ushort_t* __restrict__ Hp = (mode == 0) ? Qh : Kh;
    ushort_t* __restrict__ Lp = (mode == 0) ? Ql : Kl;
    #pragma unroll
    for (int mf = 0; mf < 4; mf++)
      #pragma unroll
      for (int nf = 0; nf < 4; nf++) {
        const int col = col0 + wn * 64 + nf * 16 + l4;
        const int p = (col & (DH - 1)) >> 1;
        const float fr = exp2f((float)p * -0.41524101186092030f);
        const float sgn = (col & 1) ? 1.0f : -1.0f;
        #pragma unroll
        for (int j = 0; j < 4; j++) {
          const int grow = row0 + wm * 64 + mf * 16 + lh * 4 + j;
          const float s = (float)(grow & (SEQ - 1));
          float sn, cs;
          sincosf(s * fr, &sn, &cs);
          const float val = acc[mf][nf][j];
          const float par = __shfl_xor(val, 1);
          const float out = val * cs + par * (sgn * sn);
          const float xsc = out * scale;
          const unsigned short hb = f2bf(xsc);
          Hp[(size_t)grow * DM + col] = hb;
          Lp[(size_t)grow * DM + col] = f2bf(xsc - bf2f(hb));
        }
      }
  } else if (mode == 2) {
    #pragma unroll
    for (int mf = 0; mf < 4; mf++)
      #pragma unroll
      for (int nf = 0; nf < 4; nf++) {
        const int col = col0 + wn * 64 + nf * 16 + l4;
        const int hh = col >> 6, dd = col & (DH - 1);
        #pragma unroll
        for (int j = 0; j < 4; j++) {
          const int grow = row0 + wm * 64 + mf * 16 + lh * 4 + j;
          const int b = grow >> 11, ss = grow & (SEQ - 1);
          Vt[((size_t)((b * NH + hh) * DH + dd)) * SEQ + ss] = f2bf(acc[mf][nf][j]);
        }
      }
  } else {
    #pragma unroll
    for (int mf = 0; mf < 4; mf++)
      #pragma unroll
      for (int nf = 0; nf < 4; nf++) {
        const int col = col0 + wn * 64 + nf * 16 + l4;
        #pragma unroll
        for (int j = 0; j < 4; j++) {
          const int grow = row0 + wm * 64 + mf * 16 + lh * 4 + j;
          Cf[(size_t)grow * DM + col] = acc[mf][nf][j];
        }
      }
  }
}

// ---------------------------------------------------------------------------
// MFMA flash attention (unchanged from round 3 — verified).
// ---------------------------------------------------------------------------
__global__ __launch_bounds__(256)
void attn_mfma(const ushort_t* __restrict__ Qh, const ushort_t* __restrict__ Ql,
               const ushort_t* __restrict__ Kh, const ushort_t* __restrict__ Kl,
               const ushort_t* __restrict__ Vt, float* __restrict__ A)
{
  __shared__ __align__(16) ushort_t Khl[2][2][64][32];
  __shared__ __align__(16) ushort_t Vtl[64][72];
  __shared__ __align__(16) ushort_t Pl[4][16][72];

  const int t = threadIdx.x;
  const int lane = t & 63, w = t >> 6;
  const int l4 = lane & 15, lh = lane >> 4;
  const int qblk = blockIdx.x, bh = blockIdx.y;
  const int b = bh >> 4, h = bh & 15;
  const int q0w = qblk * 64 + w * 16;

  short8v aq[2][2];
  {
    const size_t qoff = (size_t)((b * SEQ) + (q0w + l4)) * DM + h * DH;
    #pragma unroll
    for (int db = 0; db < 2; db++) {
      aq[0][db] = *(const short8v*)&Qh[qoff + db * 32 + lh * 8];
      aq[1][db] = *(const short8v*)&Ql[qoff + db * 32 + lh * 8];
    }
  }

  f32x4 o[4];
  float m[4], ls[4];
  #pragma unroll
  for (int j = 0; j < 4; j++) {
    o[j] = (f32x4){0.f, 0.f, 0.f, 0.f};
    m[j] = -1e30f; ls[j] = 0.f;
  }

  const ushort_t* __restrict__ Vg = Vt + (size_t)bh * DH * SEQ;
  const int nt = qblk + 1;

  for (int kt = 0; kt < nt; kt++) {
    {
      const int kr = t >> 2, kc = t & 3;
      const size_t koff = (size_t)(b * SEQ + kt * 64 + kr) * DM + h * DH;
      #pragma unroll
      for (int db = 0; db < 2; db++) {
        short8v vh = *(const short8v*)&Kh[koff + db * 32 + kc * 8];
        short8v vl = *(const short8v*)&Kl[koff + db * 32 + kc * 8];
        *(short8v*)&Khl[0][db][kr][kc * 8] = vh;
        *(short8v*)&Khl[1][db][kr][kc * 8] = vl;
      }
      short8v vv0 = *(const short8v*)&Vg[(size_t)kr * SEQ + kt * 64 + kc * 8];
      short8v vv1 = *(const short8v*)&Vg[(size_t)kr * SEQ + kt * 64 + kc * 8 + 32];
      *(short8v*)&Vtl[kr][kc * 8]      = vv0;
      *(short8v*)&Vtl[kr][kc * 8 + 32] = vv1;
    }
    __syncthreads();

    f32x4 s[4];
    #pragma unroll
    for (int n = 0; n < 4; n++) s[n] = (f32x4){0.f, 0.f, 0.f, 0.f};
    #pragma unroll
    for (int n = 0; n < 4; n++) {
      const int krow = n * 16 + l4;
      #pragma unroll
      for (int db = 0; db < 2; db++) {
        short8v bhv = *(const short8v*)&Khl[0][db][krow][lh * 8];
        short8v blv = *(const short8v*)&Khl[1][db][krow][lh * 8];
        s[n] = __builtin_amdgcn_mfma_f32_16x16x32_bf16(aq[0][db], bhv, s[n], 0, 0, 0);
        s[n] = __builtin_amdgcn_mfma_f32_16x16x32_bf16(aq[0][db], blv, s[n], 0, 0, 0);
        s[n] = __builtin_amdgcn_mfma_f32_16x16x32_bf16(aq[1][db], bhv, s[n], 0, 0, 0);
      }
    }

    const int kb = kt * 64;
    #pragma unroll
    for (int j = 0; j < 4; j++) {
      const int qg = q0w + lh * 4 + j;
      #pragma unroll
      for (int n = 0; n < 4; n++)
        if (kb + n * 16 + l4 > qg) s[n][j] = -1e30f;

      float v = fmaxf(fmaxf(s[0][j], s[1][j]), fmaxf(s[2][j], s[3][j]));
      #pragma unroll
      for (int off = 1; off < 16; off <<= 1) v = fmaxf(v, __shfl_xor(v, off));
      const float nm = fmaxf(m[j], v);
      const float corr = __expf(m[j] - nm);
      m[j] = nm;
      float rs = 0.f;
      #pragma unroll
      for (int n = 0; n < 4; n++) {
        const float p = __expf(s[n][j] - nm);
        s[n][j] = p;
        rs += p;
      }
      #pragma unroll
      for (int off = 1; off < 16; off <<= 1) rs += __shfl_xor(rs, off);
      ls[j] = ls[j] * corr + rs;
      #pragma unroll
      for (int df = 0; df < 4; df++) o[df][j] *= corr;
    }

    #pragma unroll
    for (int n = 0; n < 4; n++)
      #pragma unroll
      for (int j = 0; j < 4; j++)
        Pl[w][lh * 4 + j][n * 16 + l4] = f2bf(s[n][j]);

    #pragma unroll
    for (int kb2 = 0; kb2 < 2; kb2++) {
      short8v ap = *(const short8v*)&Pl[w][l4][kb2 * 32 + lh * 8];
      #pragma unroll
      for (int df = 0; df < 4; df++) {
        short8v bv = *(const short8v*)&Vtl[df * 16 + l4][kb2 * 32 + lh * 8];
        o[df] = __builtin_amdgcn_mfma_f32_16x16x32_bf16(ap, bv, o[df], 0, 0, 0);
      }
    }
    __syncthreads();
  }

  #pragma unroll
  for (int j = 0; j < 4; j++) {
    const float inv = 1.0f / ls[j];
    const size_t row = (size_t)(b * SEQ + q0w + lh * 4 + j);
    #pragma unroll
    for (int df = 0; df < 4; df++)
      A[row * DM + h * DH + df * 16 + l4] = o[df][j] * inv;
  }
}

// ---------------------------------------------------------------------------
// ws layout (56 MB, within proven budget):
//   0MB: Xh(8) Xl(8)      -> after QKV: Afp fp32 (16)
//  16MB: Kh(8) Kl(8)      -> after attn: AAh(8) AAl(8)
//  32MB: Vt(8)
//  40MB: WT 4x(hi 2MB + lo 2MB) = 16
// d_out: Qh(8) Ql(8) scratch, then final fp32 out (16).
// ---------------------------------------------------------------------------
extern "C" void kernel_launch(void* const* d_in, const int* in_sizes, int n_in,
                              void* d_out, int out_size, void* d_ws, size_t ws_size,
                              hipStream_t stream) {
  const float* x  = (const float*)d_in[0];
  const float* qw = (const float*)d_in[1];
  const float* kw = (const float*)d_in[2];
  const float* vw = (const float*)d_in[3];
  const float* ow = (const float*)d_in[4];

  char* ws = (char*)d_ws;
  ushort_t* Xh  = (ushort_t*)ws;
  ushort_t* Xl  = Xh + 4194304;
  float*    Afp = (float*)ws;
  ushort_t* Kh  = (ushort_t*)(ws + (16u << 20));
  ushort_t* Kl  = Kh + 4194304;
  ushort_t* AAh = Kh;
  ushort_t* AAl = Kl;
  ushort_t* Vt  = (ushort_t*)(ws + (32u << 20));
  ushort_t* WT  = (ushort_t*)(ws + (40u << 20));
  ushort_t* Qh  = (ushort_t*)d_out;
  ushort_t* Ql  = Qh + 4194304;
  float*    out = (float*)d_out;

  dim3 blk(256);
  split_f32<<<dim3(2048), blk, 0, stream>>>(x, Xh, Xl, 524288);
  wtrans<<<dim3(16, 16, 4), blk, 0, stream>>>(qw, kw, vw, ow, WT);
  mfma_gemm<<<dim3(8, 32, 3), blk, 0, stream>>>(
      Xh, Xl, WT, 0, Qh, Ql, Kh, Kl, Vt, nullptr);
  attn_mfma<<<dim3(SEQ / 64, BATCH * NH), blk, 0, stream>>>(Qh, Ql, Kh, Kl, Vt, Afp);
  split_f32<<<dim3(2048), blk, 0, stream>>>(Afp, AAh, AAl, 524288);
  mfma_gemm<<<dim3(8, 32, 1), blk, 0, stream>>>(
      AAh, AAl, WT, 3, nullptr, nullptr, nullptr, nullptr, nullptr, out);
}

// Round 5
// 297.384 us; speedup vs baseline: 2.9465x; 2.9465x over previous
//
#include <hip/hip_runtime.h>
#include <hip/hip_bf16.h>
#include <math.h>

#define SEQ    2048
#define BATCH  2
#define DM     1024
#define NH     16
#define DH     64
#define BS_ROWS 4096
#define KDIM   1024

typedef __attribute__((ext_vector_type(8))) short short8v;
typedef __attribute__((ext_vector_type(4))) float f32x4;
typedef unsigned short ushort_t;

__device__ __forceinline__ unsigned short f2bf(float f) {
  union { float f; unsigned u; } v; v.f = f;
  unsigned r = (v.u + 0x7FFF + ((v.u >> 16) & 1)) >> 16;
  return (unsigned short)r;
}
__device__ __forceinline__ float bf2f(unsigned short h) {
  union { unsigned u; float f; } v; v.u = ((unsigned)h) << 16;
  return v.f;
}

// async global->LDS, 16B per lane; lds ptr must be wave-uniform base (+lane*16 implied)
__device__ __forceinline__ void gl16(const void* g, void* l) {
  __builtin_amdgcn_global_load_lds(
      (const __attribute__((address_space(1))) unsigned int*)g,
      (__attribute__((address_space(3))) unsigned int*)l,
      16, 0, 0);
}

// ---------------------------------------------------------------------------
// fp32 -> hi/lo bf16 split (8 elems/thread)
// ---------------------------------------------------------------------------
__global__ __launch_bounds__(256)
void split_f32(const float* __restrict__ src, ushort_t* __restrict__ h,
               ushort_t* __restrict__ l, int n8)
{
  const int i = blockIdx.x * 256 + threadIdx.x;
  if (i >= n8) return;
  const float4 v0 = ((const float4*)src)[2 * i];
  const float4 v1 = ((const float4*)src)[2 * i + 1];
  const float vals[8] = {v0.x, v0.y, v0.z, v0.w, v1.x, v1.y, v1.z, v1.w};
  short8v hv, lv;
  #pragma unroll
  for (int e = 0; e < 8; e++) {
    const unsigned short hb = f2bf(vals[e]);
    hv[e] = (short)hb;
    lv[e] = (short)f2bf(vals[e] - bf2f(hb));
  }
  ((short8v*)h)[i] = hv;
  ((short8v*)l)[i] = lv;
}

// ---------------------------------------------------------------------------
// weight transpose + split: Wt[z][hi][n][k] = hi(W[k][n]), Wt[z][lo][n][k] = lo
// ---------------------------------------------------------------------------
__global__ __launch_bounds__(256)
void wtrans(const float* __restrict__ w0, const float* __restrict__ w1,
            const float* __restrict__ w2, const float* __restrict__ w3,
            ushort_t* __restrict__ WT)
{
  __shared__ float tile[64][65];
  const int z = blockIdx.z;
  const float* __restrict__ W = (z == 0) ? w0 : (z == 1) ? w1 : (z == 2) ? w2 : w3;
  ushort_t* __restrict__ Oh = WT + (size_t)z * 2097152;
  ushort_t* __restrict__ Ol = Oh + 1048576;

  const int n0 = blockIdx.x * 64, k0 = blockIdx.y * 64;
  const int r  = threadIdx.x >> 2;
  const int c0 = (threadIdx.x & 3) * 16;

  #pragma unroll
  for (int i = 0; i < 4; i++) {
    const float4 v = *(const float4*)&W[(size_t)(k0 + r) * KDIM + n0 + c0 + 4 * i];
    tile[r][c0 + 4 * i + 0] = v.x; tile[r][c0 + 4 * i + 1] = v.y;
    tile[r][c0 + 4 * i + 2] = v.z; tile[r][c0 + 4 * i + 3] = v.w;
  }
  __syncthreads();

  #pragma unroll
  for (int c = 0; c < 2; c++) {
    short8v hv, lv;
    #pragma unroll
    for (int e = 0; e < 8; e++) {
      const float x = tile[c0 + c * 8 + e][r];
      const unsigned short hb = f2bf(x);
      hv[e] = (short)hb;
      lv[e] = (short)f2bf(x - bf2f(hb));
    }
    const size_t off = (size_t)(n0 + r) * KDIM + k0 + c0 + c * 8;
    *(short8v*)&Oh[off] = hv;
    *(short8v*)&Ol[off] = lv;
  }
}

// ---------------------------------------------------------------------------
// Split-bf16 MFMA GEMM. All per-thread state in NAMED registers (no arrays
// in the k-loop -> nothing can demote to scratch).
// ---------------------------------------------------------------------------
#define MM3(Ah_, Al_, Bh_, Bl_, C_)                                          \
  C_ = __builtin_amdgcn_mfma_f32_16x16x32_bf16(Ah_, Bh_, C_, 0, 0, 0);       \
  C_ = __builtin_amdgcn_mfma_f32_16x16x32_bf16(Ah_, Bl_, C_, 0, 0, 0);       \
  C_ = __builtin_amdgcn_mfma_f32_16x16x32_bf16(Al_, Bh_, C_, 0, 0, 0);

__global__ __launch_bounds__(256, 2)
void mfma_gemm(const ushort_t* __restrict__ Ah, const ushort_t* __restrict__ Al,
               const ushort_t* __restrict__ WT, int zbase,
               ushort_t* __restrict__ Qh, ushort_t* __restrict__ Ql,
               ushort_t* __restrict__ Kh, ushort_t* __restrict__ Kl,
               ushort_t* __restrict__ Vt, float* __restrict__ Cf)
{
  const int mode = zbase + blockIdx.z;
  const ushort_t* __restrict__ Bh = WT + (size_t)mode * 2097152;
  const ushort_t* __restrict__ Bl = Bh + 1048576;

  __shared__ ushort_t Ash[128][32];
  __shared__ ushort_t Asl[128][32];
  __shared__ ushort_t Bsh[128][32];
  __shared__ ushort_t Bsl[128][32];

  const int t = threadIdx.x;
  const int lane = t & 63, w = t >> 6;
  const int l4 = lane & 15, lh = lane >> 4;
  const int wm = w >> 1, wn = w & 1;
  const int row0 = blockIdx.y * 128, col0 = blockIdx.x * 128;

  const int srow = t >> 2;           // 0..63
  const int scol = (t & 3) * 8;      // 0,8,16,24

  f32x4 c00 = {0,0,0,0}, c01 = {0,0,0,0}, c02 = {0,0,0,0}, c03 = {0,0,0,0};
  f32x4 c10 = {0,0,0,0}, c11 = {0,0,0,0}, c12 = {0,0,0,0}, c13 = {0,0,0,0};
  f32x4 c20 = {0,0,0,0}, c21 = {0,0,0,0}, c22 = {0,0,0,0}, c23 = {0,0,0,0};
  f32x4 c30 = {0,0,0,0}, c31 = {0,0,0,0}, c32 = {0,0,0,0}, c33 = {0,0,0,0};

  const int rA = wm * 64 + l4;       // A-frag base row
  const int rB = wn * 64 + l4;       // B-frag base row
  const int cF = lh * 8;             // frag k-col

  for (int k0 = 0; k0 < KDIM; k0 += 32) {
    #pragma unroll
    for (int r = 0; r < 2; r++) {
      const int row = srow + r * 64;
      const size_t gA = (size_t)(row0 + row) * KDIM + k0 + scol;
      const size_t gB = (size_t)(col0 + row) * KDIM + k0 + scol;
      const int lo = w * 1024 + r * 4096;     // byte offset (wave-uniform)
      gl16(Ah + gA, (char*)Ash + lo);
      gl16(Al + gA, (char*)Asl + lo);
      gl16(Bh + gB, (char*)Bsh + lo);
      gl16(Bl + gB, (char*)Bsl + lo);
    }
    __syncthreads();

    const short8v ah0 = *(const short8v*)&Ash[rA +  0][cF];
    const short8v ah1 = *(const short8v*)&Ash[rA + 16][cF];
    const short8v ah2 = *(const short8v*)&Ash[rA + 32][cF];
    const short8v ah3 = *(const short8v*)&Ash[rA + 48][cF];
    const short8v al0 = *(const short8v*)&Asl[rA +  0][cF];
    const short8v al1 = *(const short8v*)&Asl[rA + 16][cF];
    const short8v al2 = *(const short8v*)&Asl[rA + 32][cF];
    const short8v al3 = *(const short8v*)&Asl[rA + 48][cF];
    const short8v bh0 = *(const short8v*)&Bsh[rB +  0][cF];
    const short8v bh1 = *(const short8v*)&Bsh[rB + 16][cF];
    const short8v bh2 = *(const short8v*)&Bsh[rB + 32][cF];
    const short8v bh3 = *(const short8v*)&Bsh[rB + 48][cF];
    const short8v bl0 = *(const short8v*)&Bsl[rB +  0][cF];
    const short8v bl1 = *(const short8v*)&Bsl[rB + 16][cF];
    const short8v bl2 = *(const short8v*)&Bsl[rB + 32][cF];
    const short8v bl3 = *(const short8v*)&Bsl[rB + 48][cF];

    MM3(ah0, al0, bh0, bl0, c00)  MM3(ah0, al0, bh1, bl1, c01)
    MM3(ah0, al0, bh2, bl2, c02)  MM3(ah0, al0, bh3, bl3, c03)
    MM3(ah1, al1, bh0, bl0, c10)  MM3(ah1, al1, bh1, bl1, c11)
    MM3(ah1, al1, bh2, bl2, c12)  MM3(ah1, al1, bh3, bl3, c13)
    MM3(ah2, al2, bh0, bl0, c20)  MM3(ah2, al2, bh1, bl1, c21)
    MM3(ah2, al2, bh2, bl2, c22)  MM3(ah2, al2, bh3, bl3, c23)
    MM3(ah3, al3, bh0, bl0, c30)  MM3(ah3, al3, bh1, bl1, c31)
    MM3(ah3, al3, bh2, bl2, c32)  MM3(ah3, al3, bh3, bl3, c33)
    __syncthreads();
  }

  // gather named accs for the (verified) epilogue code
  f32x4 acc[4][4];
  acc[0][0]=c00; acc[0][1]=c01; acc[0][2]=c02; acc[0][3]=c03;
  acc[1][0]=c10; acc[1][1]=c11; acc[1][2]=c12; acc[1][3]=c13;
  acc[2][0]=c20; acc[2][1]=c21; acc[2][2]=c22; acc[2][3]=c23;
  acc[3][0]=c30; acc[3][1]=c31; acc[3][2]=c32; acc[3][3]=c33;

  if (mode <= 1) {
    const float scale = (mode == 0) ? 0.03125f : 1.0f;
    ushort_t* __restrict__ Hp = (mode == 0) ? Qh : Kh;
    ushort_t* __restrict__ Lp = (mode == 0) ? Ql : Kl;
    #pragma unroll
    for (int mf = 0; mf < 4; mf++)
      #pragma unroll
      for (int nf = 0; nf < 4; nf++) {
        const int col = col0 + wn * 64 + nf * 16 + l4;
        const int p = (col & (DH - 1)) >> 1;
        const float fr = exp2f((float)p * -0.41524101186092030f);
        const float sgn = (col & 1) ? 1.0f : -1.0f;
        #pragma unroll
        for (int j = 0; j < 4; j++) {
          const int grow = row0 + wm * 64 + mf * 16 + lh * 4 + j;
          const float s = (float)(grow & (SEQ - 1));
          float sn, cs;
          sincosf(s * fr, &sn, &cs);
          const float val = acc[mf][nf][j];
          const float par = __shfl_xor(val, 1);
          const float out = val * cs + par * (sgn * sn);
          const float xsc = out * scale;
          const unsigned short hb = f2bf(xsc);
          Hp[(size_t)grow * DM + col] = hb;
          Lp[(size_t)grow * DM + col] = f2bf(xsc - bf2f(hb));
        }
      }
  } else if (mode == 2) {
    #pragma unroll
    for (int mf = 0; mf < 4; mf++)
      #pragma unroll
      for (int nf = 0; nf < 4; nf++) {
        const int col = col0 + wn * 64 + nf * 16 + l4;
        const int hh = col >> 6, dd = col & (DH - 1);
        #pragma unroll
        for (int j = 0; j < 4; j++) {
          const int grow = row0 + wm * 64 + mf * 16 + lh * 4 + j;
          const int b = grow >> 11, ss = grow & (SEQ - 1);
          Vt[((size_t)((b * NH + hh) * DH + dd)) * SEQ + ss] = f2bf(acc[mf][nf][j]);
        }
      }
  } else {
    #pragma unroll
    for (int mf = 0; mf < 4; mf++)
      #pragma unroll
      for (int nf = 0; nf < 4; nf++) {
        const int col = col0 + wn * 64 + nf * 16 + l4;
        #pragma unroll
        for (int j = 0; j < 4; j++) {
          const int grow = row0 + wm * 64 + mf * 16 + lh * 4 + j;
          Cf[(size_t)grow * DM + col] = acc[mf][nf][j];
        }
      }
  }
}

// ---------------------------------------------------------------------------
// MFMA flash attention (unchanged — verified).
// ---------------------------------------------------------------------------
__global__ __launch_bounds__(256)
void attn_mfma(const ushort_t* __restrict__ Qh, const ushort_t* __restrict__ Ql,
               const ushort_t* __restrict__ Kh, const ushort_t* __restrict__ Kl,
               const ushort_t* __restrict__ Vt, float* __restrict__ A)
{
  __shared__ __align__(16) ushort_t Khl[2][2][64][32];
  __shared__ __align__(16) ushort_t Vtl[64][72];
  __shared__ __align__(16) ushort_t Pl[4][16][72];

  const int t = threadIdx.x;
  const int lane = t & 63, w = t >> 6;
  const int l4 = lane & 15, lh = lane >> 4;
  const int qblk = blockIdx.x, bh = blockIdx.y;
  const int b = bh >> 4, h = bh & 15;
  const int q0w = qblk * 64 + w * 16;

  short8v aq[2][2];
  {
    const size_t qoff = (size_t)((b * SEQ) + (q0w + l4)) * DM + h * DH;
    #pragma unroll
    for (int db = 0; db < 2; db++) {
      aq[0][db] = *(const short8v*)&Qh[qoff + db * 32 + lh * 8];
      aq[1][db] = *(const short8v*)&Ql[qoff + db * 32 + lh * 8];
    }
  }

  f32x4 o[4];
  float m[4], ls[4];
  #pragma unroll
  for (int j = 0; j < 4; j++) {
    o[j] = (f32x4){0.f, 0.f, 0.f, 0.f};
    m[j] = -1e30f; ls[j] = 0.f;
  }

  const ushort_t* __restrict__ Vg = Vt + (size_t)bh * DH * SEQ;
  const int nt = qblk + 1;

  for (int kt = 0; kt < nt; kt++) {
    {
      const int kr = t >> 2, kc = t & 3;
      const size_t koff = (size_t)(b * SEQ + kt * 64 + kr) * DM + h * DH;
      #pragma unroll
      for (int db = 0; db < 2; db++) {
        short8v vh = *(const short8v*)&Kh[koff + db * 32 + kc * 8];
        short8v vl = *(const short8v*)&Kl[koff + db * 32 + kc * 8];
        *(short8v*)&Khl[0][db][kr][kc * 8] = vh;
        *(short8v*)&Khl[1][db][kr][kc * 8] = vl;
      }
      short8v vv0 = *(const short8v*)&Vg[(size_t)kr * SEQ + kt * 64 + kc * 8];
      short8v vv1 = *(const short8v*)&Vg[(size_t)kr * SEQ + kt * 64 + kc * 8 + 32];
      *(short8v*)&Vtl[kr][kc * 8]      = vv0;
      *(short8v*)&Vtl[kr][kc * 8 + 32] = vv1;
    }
    __syncthreads();

    f32x4 s[4];
    #pragma unroll
    for (int n = 0; n < 4; n++) s[n] = (f32x4){0.f, 0.f, 0.f, 0.f};
    #pragma unroll
    for (int n = 0; n < 4; n++) {
      const int krow = n * 16 + l4;
      #pragma unroll
      for (int db = 0; db < 2; db++) {
        short8v bhv = *(const short8v*)&Khl[0][db][krow][lh * 8];
        short8v blv = *(const short8v*)&Khl[1][db][krow][lh * 8];
        s[n] = __builtin_amdgcn_mfma_f32_16x16x32_bf16(aq[0][db], bhv, s[n], 0, 0, 0);
        s[n] = __builtin_amdgcn_mfma_f32_16x16x32_bf16(aq[0][db], blv, s[n], 0, 0, 0);
        s[n] = __builtin_amdgcn_mfma_f32_16x16x32_bf16(aq[1][db], bhv, s[n], 0, 0, 0);
      }
    }

    const int kb = kt * 64;
    #pragma unroll
    for (int j = 0; j < 4; j++) {
      const int qg = q0w + lh * 4 + j;
      #pragma unroll
      for (int n = 0; n < 4; n++)
        if (kb + n * 16 + l4 > qg) s[n][j] = -1e30f;

      float v = fmaxf(fmaxf(s[0][j], s[1][j]), fmaxf(s[2][j], s[3][j]));
      #pragma unroll
      for (int off = 1; off < 16; off <<= 1) v = fmaxf(v, __shfl_xor(v, off));
      const float nm = fmaxf(m[j], v);
      const float corr = __expf(m[j] - nm);
      m[j] = nm;
      float rs = 0.f;
      #pragma unroll
      for (int n = 0; n < 4; n++) {
        const float p = __expf(s[n][j] - nm);
        s[n][j] = p;
        rs += p;
      }
      #pragma unroll
      for (int off = 1; off < 16; off <<= 1) rs += __shfl_xor(rs, off);
      ls[j] = ls[j] * corr + rs;
      #pragma unroll
      for (int df = 0; df < 4; df++) o[df][j] *= corr;
    }

    #pragma unroll
    for (int n = 0; n < 4; n++)
      #pragma unroll
      for (int j = 0; j < 4; j++)
        Pl[w][lh * 4 + j][n * 16 + l4] = f2bf(s[n][j]);

    #pragma unroll
    for (int kb2 = 0; kb2 < 2; kb2++) {
      short8v ap = *(const short8v*)&Pl[w][l4][kb2 * 32 + lh * 8];
      #pragma unroll
      for (int df = 0; df < 4; df++) {
        short8v bv = *(const short8v*)&Vtl[df * 16 + l4][kb2 * 32 + lh * 8];
        o[df] = __builtin_amdgcn_mfma_f32_16x16x32_bf16(ap, bv, o[df], 0, 0, 0);
      }
    }
    __syncthreads();
  }

  #pragma unroll
  for (int j = 0; j < 4; j++) {
    const float inv = 1.0f / ls[j];
    const size_t row = (size_t)(b * SEQ + q0w + lh * 4 + j);
    #pragma unroll
    for (int df = 0; df < 4; df++)
      A[row * DM + h * DH + df * 16 + l4] = o[df][j] * inv;
  }
}

// ---------------------------------------------------------------------------
extern "C" void kernel_launch(void* const* d_in, const int* in_sizes, int n_in,
                              void* d_out, int out_size, void* d_ws, size_t ws_size,
                              hipStream_t stream) {
  const float* x  = (const float*)d_in[0];
  const float* qw = (const float*)d_in[1];
  const float* kw = (const float*)d_in[2];
  const float* vw = (const float*)d_in[3];
  const float* ow = (const float*)d_in[4];

  char* ws = (char*)d_ws;
  ushort_t* Xh  = (ushort_t*)ws;
  ushort_t* Xl  = Xh + 4194304;
  float*    Afp = (float*)ws;
  ushort_t* Kh  = (ushort_t*)(ws + (16u << 20));
  ushort_t* Kl  = Kh + 4194304;
  ushort_t* AAh = Kh;
  ushort_t* AAl = Kl;
  ushort_t* Vt  = (ushort_t*)(ws + (32u << 20));
  ushort_t* WT  = (ushort_t*)(ws + (40u << 20));
  ushort_t* Qh  = (ushort_t*)d_out;
  ushort_t* Ql  = Qh + 4194304;
  float*    out = (float*)d_out;

  dim3 blk(256);
  split_f32<<<dim3(2048), blk, 0, stream>>>(x, Xh, Xl, 524288);
  wtrans<<<dim3(16, 16, 4), blk, 0, stream>>>(qw, kw, vw, ow, WT);
  mfma_gemm<<<dim3(8, 32, 3), blk, 0, stream>>>(
      Xh, Xl, WT, 0, Qh, Ql, Kh, Kl, Vt, nullptr);
  attn_mfma<<<dim3(SEQ / 64, BATCH * NH), blk, 0, stream>>>(Qh, Ql, Kh, Kl, Vt, Afp);
  split_f32<<<dim3(2048), blk, 0, stream>>>(Afp, AAh, AAl, 524288);
  mfma_gemm<<<dim3(8, 32, 1), blk, 0, stream>>>(
      AAh, AAl, WT, 3, nullptr, nullptr, nullptr, nullptr, nullptr, out);
}